// Round 5
// baseline (673.924 us; speedup 1.0000x reference)
//
#include <hip/hip_runtime.h>

typedef unsigned int uint;
typedef unsigned short ushort;
typedef __bf16 v8b __attribute__((ext_vector_type(8)));
typedef float v4f __attribute__((ext_vector_type(4)));

#define NN 100000
#define EE 3200000
#define DD 128

// counting-sort CSR build: 391 buckets x 256 nodes
#define BSH 8
#define BSZ 256                    // nodes per bucket (1<<BSH)
#define NB ((NN + BSZ - 1) / BSZ)  // 391
#define CAP 16384                  // per-bucket capacity (avg fill ~8184)
#define EPB 8192                   // edges per block in k_bucket
#define NBLK1 ((EE + EPB - 1) / EPB)  // 391

// k_lin: block = 4 waves x 32 rows = 128 rows
#define LGRID ((NN + 127) / 128)  // 782

// k_prep block ranges
#define PREP_EMB 12500            // NN*DD/4/256
#define PREP_WB 16                // blocks per weight matrix (DD*DD/4/256)
#define PREP_BIAS (PREP_EMB + 4 * PREP_WB)      // 12564
#define PREP_ZERO (PREP_BIAS + 1)               // 12565
#define PREP_GRID (PREP_ZERO + 2)               // 12567

// ---- all scratch static: zero dependence on ws_size ----
__device__ __attribute__((aligned(256))) int g_offs[NN + 1];
__device__ __attribute__((aligned(256))) int g_flag[2];    // [0]=edge is64, [1]=float is fp32
__device__ __attribute__((aligned(256))) int g_bcnt2[NB];  // bucket fill counts
__device__ __attribute__((aligned(256))) int g_bbase[NB];  // bucket base offsets (excl scan)
__device__ __attribute__((aligned(256))) int g_csr[EE];
// bucketed packed edges: (local_dst<<17)|src, bucket b at [b*CAP, b*CAP+cnt)
__device__ __attribute__((aligned(256))) uint g_pairs2[(size_t)NB * CAP];
// bf16 hi/lo split representations (hi also serves as the gather array)
__device__ __attribute__((aligned(256))) ushort g_emb_h[(size_t)NN * DD];
__device__ __attribute__((aligned(256))) ushort g_emb_l[(size_t)NN * DD];
__device__ __attribute__((aligned(256))) ushort g_agg_h[(size_t)NN * DD];
__device__ __attribute__((aligned(256))) ushort g_agg_l[(size_t)NN * DD];
__device__ __attribute__((aligned(256))) ushort g_hh[(size_t)NN * DD];
__device__ __attribute__((aligned(256))) ushort g_hl[(size_t)NN * DD];
__device__ __attribute__((aligned(256))) ushort g_w_h[4][DD * DD];  // Wl0,Wr0,Wl1,Wr1
__device__ __attribute__((aligned(256))) ushort g_w_l[4][DD * DD];
__device__ __attribute__((aligned(256))) float g_biasf[2][DD];  // b0,b1

__device__ __forceinline__ float blo(uint u) { return __uint_as_float(u << 16); }
__device__ __forceinline__ float bhi(uint u) { return __uint_as_float(u & 0xffff0000u); }
__device__ __forceinline__ ushort f2b(float f) {
  uint u = __float_as_uint(f);
  u += 0x7fffu + ((u >> 16) & 1u);  // RNE
  return (ushort)(u >> 16);
}
__device__ __forceinline__ float b2f(ushort s) { return __uint_as_float(((uint)s) << 16); }

// ---- dtype detection -----------------------------------------------------
__global__ void k_detect_ei(const int* __restrict__ ei) {
  __shared__ int any;
  if (threadIdx.x == 0) any = 0;
  __syncthreads();
  int v = 0;
  for (int i = threadIdx.x; i < 2048; i += 256) v |= ei[2 * i + 1];
  if (v) atomicOr(&any, 1);
  __syncthreads();
  if (threadIdx.x == 0) g_flag[0] = (any == 0) ? 1 : 0;  // 1 => int64
}

__global__ void k_detect_f(const ushort* __restrict__ u) {
  __shared__ int bad;
  if (threadIdx.x == 0) bad = 0;
  __syncthreads();
  int b = 0;
  for (int i = threadIdx.x; i < 2048; i += 256) {
    int e = (u[2 * i] >> 7) & 0xff;
    if (e < 0x40 || e > 0x7f) b = 1;
  }
  if (b) atomicOr(&bad, 1);
  __syncthreads();
  if (threadIdx.x == 0) g_flag[1] = bad;  // 1 => fp32
}

// ---- fused preprocessing: splits + bias cvt + bucket-count zero ---------
__device__ __forceinline__ void split4(const void* __restrict__ src,
                                       ushort* __restrict__ dh,
                                       ushort* __restrict__ dl, int i) {
  float f[4];
  if (g_flag[1]) {
    float4 v = *(const float4*)((const float*)src + i);
    f[0] = v.x; f[1] = v.y; f[2] = v.z; f[3] = v.w;
  } else {
    ushort4 s = *(const ushort4*)((const ushort*)src + i);
    f[0] = b2f(s.x); f[1] = b2f(s.y); f[2] = b2f(s.z); f[3] = b2f(s.w);
  }
  ushort4 h, l;
  ushort* hp = &h.x;
  ushort* lp = &l.x;
#pragma unroll
  for (int k = 0; k < 4; k++) {
    ushort hi = f2b(f[k]);
    hp[k] = hi;
    lp[k] = f2b(f[k] - b2f(hi));
  }
  *(ushort4*)(dh + i) = h;
  *(ushort4*)(dl + i) = l;
}

__global__ void k_prep(const void* __restrict__ emb, const void* __restrict__ s0,
                       const void* __restrict__ s1, const void* __restrict__ s2,
                       const void* __restrict__ s3, const void* __restrict__ bs0,
                       const void* __restrict__ bs1) {
  int bid = blockIdx.x;
  int tid = threadIdx.x;
  if (bid < PREP_EMB) {
    int i = (bid * 256 + tid) * 4;
    split4(emb, g_emb_h, g_emb_l, i);
  } else if (bid < PREP_BIAS) {
    int wb = bid - PREP_EMB;
    int w = wb >> 4;
    int i = ((wb & 15) * 256 + tid) * 4;
    const void* src = (w == 0) ? s0 : (w == 1) ? s1 : (w == 2) ? s2 : s3;
    split4(src, &g_w_h[0][0] + w * DD * DD, &g_w_l[0][0] + w * DD * DD, i);
  } else if (bid == PREP_BIAS) {
    int which = tid >> 7;        // 0 or 1
    int i = tid & 127;
    const void* src = which ? bs1 : bs0;
    float v = g_flag[1] ? ((const float*)src)[i] : b2f(((const ushort*)src)[i]);
    g_biasf[which][i] = v;
  } else {
    int i = (bid - PREP_ZERO) * 256 + tid;
    if (i < NB) g_bcnt2[i] = 0;
  }
}

__device__ __forceinline__ int ld_src(const int* __restrict__ ei, int is64, int e) {
  int v = is64 ? ei[2 * e] : ei[e];
  return ((uint)v < (uint)NN) ? v : 0;
}
__device__ __forceinline__ int ld_dst(const int* __restrict__ ei, int is64, int e) {
  int v = is64 ? ei[2 * (EE + e)] : ei[EE + e];
  return ((uint)v < (uint)NN) ? v : 0;
}

// ---------------- CSR build (counting sort, no per-edge global atomics) ----

// One pass over the edge stream. Per-block LDS staging of packed edges +
// 391-counter LDS histogram; ONE global atomicAdd per bucket per block
// (153K total); compact appends into fixed-capacity bucket regions.
// pack = (local_dst<<17)|src  (local<256 = 8b, src<131072 = 17b).
__global__ __launch_bounds__(256) void k_bucket(const int* __restrict__ ei) {
  int is64 = g_flag[0];
  __shared__ uint s_pk[EPB];    // 32 KB
  __shared__ ushort s_bk[EPB];  // 16 KB
  __shared__ int s_cnt[NB];
  __shared__ int s_base[NB];
  for (int i = threadIdx.x; i < NB; i += 256) s_cnt[i] = 0;
  __syncthreads();
  int base = blockIdx.x * EPB;
  // phase A: load, pack, count
#pragma unroll
  for (int i = 0; i < EPB / 256; i++) {
    int li = i * 256 + threadIdx.x;
    int e = base + li;
    uint pk = 0;
    int b = -1;
    if (e < EE) {
      int d = ld_dst(ei, is64, e);
      int s = ld_src(ei, is64, e);
      b = d >> BSH;
      pk = ((uint)(d & (BSZ - 1)) << 17) | (uint)s;
      atomicAdd(&s_cnt[b], 1);
    }
    s_pk[li] = pk;
    s_bk[li] = (ushort)b;  // 0xffff sentinel when invalid
  }
  __syncthreads();
  // reserve global bases: one atomic per non-empty bucket
  for (int i = threadIdx.x; i < NB; i += 256) {
    int c = s_cnt[i];
    s_base[i] = c ? atomicAdd(&g_bcnt2[i], c) : 0;
    s_cnt[i] = 0;  // reuse as cursor
  }
  __syncthreads();
  // phase B: append
#pragma unroll
  for (int i = 0; i < EPB / 256; i++) {
    int li = i * 256 + threadIdx.x;
    int b = s_bk[li];
    if (b != 0xffff) {
      int idx = s_base[b] + atomicAdd(&s_cnt[b], 1);
      if (idx < CAP) g_pairs2[(size_t)b * CAP + idx] = s_pk[li];
    }
  }
}

// exclusive scan of bucket counts -> bucket base offsets; total -> g_offs[NN]
__global__ void k_bscan() {
  __shared__ int sd[512];
  int t = threadIdx.x;
  int v = (t < NB) ? min(g_bcnt2[t], CAP) : 0;
  sd[t] = v;
  __syncthreads();
  for (int off = 1; off < 512; off <<= 1) {
    int x = (t >= off) ? sd[t - off] : 0;
    __syncthreads();
    sd[t] += x;
    __syncthreads();
  }
  if (t < NB) g_bbase[t] = sd[t] - v;
  if (t == 511) g_offs[NN] = sd[511];
}

// One block per bucket: LDS histogram of 256 local dsts, LDS scan, write
// g_offs for its 256 nodes (exclusive ownership - no atomics), then place
// srcs into g_csr via LDS cursors. Per-block working set ~64KB -> L2-local.
__global__ __launch_bounds__(256) void k_place() {
  int b = blockIdx.x;
  int n = min(g_bcnt2[b], CAP);
  int gbase = g_bbase[b];
  const uint* pr = g_pairs2 + (size_t)b * CAP;
  __shared__ int hist[BSZ];
  __shared__ int sd[BSZ];
  __shared__ int cur[BSZ];
  int t = threadIdx.x;
  hist[t] = 0;
  __syncthreads();
  for (int e = t; e < n; e += 256) atomicAdd(&hist[pr[e] >> 17], 1);
  __syncthreads();
  int v = hist[t];
  sd[t] = v;
  __syncthreads();
  for (int off = 1; off < BSZ; off <<= 1) {
    int x = (t >= off) ? sd[t - off] : 0;
    __syncthreads();
    sd[t] += x;
    __syncthreads();
  }
  int excl = sd[t] - v;
  int node = (b << BSH) + t;
  if (node < NN) g_offs[node] = gbase + excl;
  cur[t] = excl;
  __syncthreads();
  for (int e = t; e < n; e += 256) {
    uint pk = pr[e];
    int p = atomicAdd(&cur[pk >> 17], 1);
    g_csr[gbase + p] = (int)(pk & 0x1FFFFu);
  }
}

// ------- mean aggregation: bf16 gather, fp32 accum, hi/lo bf16 out -------
// One wave per node. uint4 gather: 16 lanes cover one 256B row, so each
// wave-instruction gathers FOUR edges. Measured (r4): bound by the L2-miss
// path at ~3.7 TB/s regardless of instruction mix; reuse math says tiling
// gains <=15% -> structurally near its limit. Left unchanged.
__global__ void k_agg(const ushort* __restrict__ x) {
  int lane = threadIdx.x & 63;
  int node = (blockIdx.x * blockDim.x + threadIdx.x) >> 6;
  int beg = g_offs[node], end = g_offs[node + 1];
  int eb = lane >> 4;          // quarter-wave id: which edge in group-of-4
  int col = (lane & 15) * 8;   // 8 bf16 cols per lane
  float a[8];
#pragma unroll
  for (int i = 0; i < 8; i++) a[i] = 0.f;
  for (int c = beg; c < end; c += 64) {
    int cnt = end - c;
    if (cnt > 64) cnt = 64;
    int my = g_csr[c + (lane < cnt ? lane : cnt - 1)];
    if ((uint)my >= (uint)NN) my = 0;
    int j = 0;
    for (; j + 8 <= cnt; j += 8) {
      int s0 = __shfl(my, j + eb);
      int s1 = __shfl(my, j + 4 + eb);
      uint4 r0 = *(const uint4*)(x + (size_t)s0 * DD + col);
      uint4 r1 = *(const uint4*)(x + (size_t)s1 * DD + col);
      a[0] += blo(r0.x); a[1] += bhi(r0.x);
      a[2] += blo(r0.y); a[3] += bhi(r0.y);
      a[4] += blo(r0.z); a[5] += bhi(r0.z);
      a[6] += blo(r0.w); a[7] += bhi(r0.w);
      a[0] += blo(r1.x); a[1] += bhi(r1.x);
      a[2] += blo(r1.y); a[3] += bhi(r1.y);
      a[4] += blo(r1.z); a[5] += bhi(r1.z);
      a[6] += blo(r1.w); a[7] += bhi(r1.w);
    }
    for (; j < cnt; j += 4) {
      int e = j + eb;
      int s = __shfl(my, e < cnt ? e : 0);
      float w = e < cnt ? 1.f : 0.f;
      uint4 r = *(const uint4*)(x + (size_t)s * DD + col);
      a[0] = fmaf(blo(r.x), w, a[0]); a[1] = fmaf(bhi(r.x), w, a[1]);
      a[2] = fmaf(blo(r.y), w, a[2]); a[3] = fmaf(bhi(r.y), w, a[3]);
      a[4] = fmaf(blo(r.z), w, a[4]); a[5] = fmaf(bhi(r.z), w, a[5]);
      a[6] = fmaf(blo(r.w), w, a[6]); a[7] = fmaf(bhi(r.w), w, a[7]);
    }
  }
#pragma unroll
  for (int i = 0; i < 8; i++) {
    a[i] += __shfl_xor(a[i], 16);
    a[i] += __shfl_xor(a[i], 32);
  }
  int deg = end - beg;
  float inv = deg > 0 ? 1.0f / (float)deg : 0.f;
  if (lane < 16) {
    uint4 h, l;
    uint* hp = &h.x;
    uint* lp = &l.x;
#pragma unroll
    for (int k = 0; k < 4; k++) {
      float f0 = a[2 * k] * inv, f1 = a[2 * k + 1] * inv;
      ushort h0 = f2b(f0), h1 = f2b(f1);
      ushort l0 = f2b(f0 - b2f(h0)), l1 = f2b(f1 - b2f(h1));
      hp[k] = (uint)h0 | ((uint)h1 << 16);
      lp[k] = (uint)l0 | ((uint)l1 << 16);
    }
    size_t o = (size_t)node * DD + col;
    *(uint4*)(g_agg_h + o) = h;
    *(uint4*)(g_agg_l + o) = l;
  }
}

// ------- MFMA linear, bf16x3: out = act(A1@Wl^T + b + A2@Wr^T) -----------
// (ah+al)(bh+bl) ~= ah*bh + ah*bl + al*bh  (error ~2^-16 rel, fp32 accum)
// Block = 4 waves x 32 rows = 128 rows. Weights staged in LDS in 4 stages
// of 32 W-rows x 4 arrays (32 KB), XOR-swizzled (cb16 ^= n&15) so each
// quarter-wave ds_read_b128 hits 16 distinct 16B bank-slots. Write and
// read use the same bijection -> correctness independent of swizzle.
// Replaces per-wave global B-loads (16 per nt-iter, ~200cy chains) with
// ~40cy LDS reads; per-block weight traffic drops 4x.
// A frag: row=lane&15, k=(lane>>4)*8+j.  B frag: W row n=lane&15, same k.
// C/D: col=lane&15, row=(lane>>4)*4+reg.   (layouts verified: r4===r5 bitwise)
// MODE 0: bias+ReLU -> h hi/lo bf16.  MODE 1: bias+L2-normalize -> fp32 out.

#define MFMA16(a, b, c) __builtin_amdgcn_mfma_f32_16x16x32_bf16(a, b, c, 0, 0, 0)

template <int MODE>
__global__ __launch_bounds__(256, 3) void k_lin(
    const ushort* __restrict__ A1h, const ushort* __restrict__ A1l,
    const ushort* __restrict__ A2h, const ushort* __restrict__ A2l,
    const ushort* __restrict__ Wlh, const ushort* __restrict__ Wll,
    const ushort* __restrict__ Wrh, const ushort* __restrict__ Wrl,
    const float* __restrict__ bias, void* out0, ushort* __restrict__ outlo) {
  __shared__ ushort smem[16384];  // 4 arrays x 32 rows x 128 cols, 32 KB
  int tid = threadIdx.x;
  int lane = tid & 63;
  int wid = tid >> 6;
  int m = lane & 15, q = lane >> 4;
  int row0 = blockIdx.x * 128 + wid * 32;
  // clamp A-row addresses for the tail block (stores are guarded; no early
  // return because all waves must reach the staging __syncthreads)
  int arow0 = row0 + m;      if (arow0 > NN - 1) arow0 = NN - 1;
  int arow1 = row0 + 16 + m; if (arow1 > NN - 1) arow1 = NN - 1;
  size_t aoff0 = (size_t)arow0 * DD + q * 8;
  size_t aoff1 = (size_t)arow1 * DD + q * 8;
  v4f acc[2][8];
#pragma unroll
  for (int t = 0; t < 2; t++)
#pragma unroll
    for (int nt = 0; nt < 8; nt++) acc[t][nt] = (v4f){0.f, 0.f, 0.f, 0.f};
#pragma unroll
  for (int st = 0; st < 4; st++) {
    // ---- stage W rows [st*32, st*32+32) of all 4 arrays into LDS ----
#pragma unroll
    for (int k = 0; k < 8; k++) {
      int arr = k >> 1;  // compile-time after unroll
      int n = ((k & 1) << 4) + (tid >> 4);
      int cb16 = tid & 15;
      const ushort* srcp = (arr == 0) ? Wlh : (arr == 1) ? Wll : (arr == 2) ? Wrh : Wrl;
      uint4 v = *(const uint4*)(srcp + (size_t)(st * 32 + n) * DD + cb16 * 8);
      *(uint4*)(smem + arr * 4096 + n * 128 + ((cb16 ^ (n & 15)) << 3)) = v;
    }
    __syncthreads();
#pragma unroll
    for (int ks = 0; ks < 4; ks++) {
      v8b a1h0 = *(const v8b*)(A1h + aoff0 + ks * 32);
      v8b a1l0 = *(const v8b*)(A1l + aoff0 + ks * 32);
      v8b a2h0 = *(const v8b*)(A2h + aoff0 + ks * 32);
      v8b a2l0 = *(const v8b*)(A2l + aoff0 + ks * 32);
      v8b a1h1 = *(const v8b*)(A1h + aoff1 + ks * 32);
      v8b a1l1 = *(const v8b*)(A1l + aoff1 + ks * 32);
      v8b a2h1 = *(const v8b*)(A2h + aoff1 + ks * 32);
      v8b a2l1 = *(const v8b*)(A2l + aoff1 + ks * 32);
#pragma unroll
      for (int ntl = 0; ntl < 2; ntl++) {
        int nt = st * 2 + ntl;
        int nl = ntl * 16 + m;
        int u = nl * 128 + (((q + 4 * ks) ^ m) << 3);
        v8b blh = *(const v8b*)(smem + u);
        v8b bll = *(const v8b*)(smem + 4096 + u);
        v8b brh = *(const v8b*)(smem + 8192 + u);
        v8b brl = *(const v8b*)(smem + 12288 + u);
        acc[0][nt] = MFMA16(a1h0, blh, acc[0][nt]);
        acc[0][nt] = MFMA16(a1h0, bll, acc[0][nt]);
        acc[0][nt] = MFMA16(a1l0, blh, acc[0][nt]);
        acc[0][nt] = MFMA16(a2h0, brh, acc[0][nt]);
        acc[0][nt] = MFMA16(a2h0, brl, acc[0][nt]);
        acc[0][nt] = MFMA16(a2l0, brh, acc[0][nt]);
        acc[1][nt] = MFMA16(a1h1, blh, acc[1][nt]);
        acc[1][nt] = MFMA16(a1h1, bll, acc[1][nt]);
        acc[1][nt] = MFMA16(a1l1, blh, acc[1][nt]);
        acc[1][nt] = MFMA16(a2h1, brh, acc[1][nt]);
        acc[1][nt] = MFMA16(a2h1, brl, acc[1][nt]);
        acc[1][nt] = MFMA16(a2l1, brh, acc[1][nt]);
      }
    }
    __syncthreads();
  }
  if (MODE == 0) {
    ushort* oh = (ushort*)out0;
#pragma unroll
    for (int t = 0; t < 2; t++) {
#pragma unroll
      for (int nt = 0; nt < 8; nt++) {
        float bv = bias[nt * 16 + m];
#pragma unroll
        for (int r = 0; r < 4; r++) {
          int row = row0 + t * 16 + q * 4 + r;
          if (row < NN) {
            float v = acc[t][nt][r] + bv;
            v = v > 0.f ? v : 0.f;
            ushort hi = f2b(v);
            ushort lo = f2b(v - b2f(hi));
            size_t o = (size_t)row * DD + nt * 16 + m;
            oh[o] = hi;
            outlo[o] = lo;
          }
        }
      }
    }
  } else {
    float* of = (float*)out0;
#pragma unroll
    for (int t = 0; t < 2; t++) {
#pragma unroll
      for (int r = 0; r < 4; r++) {
        float p = 0.f;
#pragma unroll
        for (int nt = 0; nt < 8; nt++) {
          float v = acc[t][nt][r] + bias[nt * 16 + m];
          acc[t][nt][r] = v;
          p += v * v;
        }
        p += __shfl_xor(p, 1);
        p += __shfl_xor(p, 2);
        p += __shfl_xor(p, 4);
        p += __shfl_xor(p, 8);
        float inv = (p > 0.f) ? 1.0f / fmaxf(sqrtf(p), 1e-12f) : 0.f;
        int row = row0 + t * 16 + q * 4 + r;
        if (row < NN) {
#pragma unroll
          for (int nt = 0; nt < 8; nt++)
            of[(size_t)row * DD + nt * 16 + m] = acc[t][nt][r] * inv;
        }
      }
    }
  }
}

// ---------------- launch ----------------

extern "C" void kernel_launch(void* const* d_in, const int* in_sizes, int n_in,
                              void* d_out, int out_size, void* d_ws, size_t ws_size,
                              hipStream_t stream) {
  const int* ei = (const int*)d_in[0];
  (void)in_sizes; (void)n_in; (void)out_size; (void)d_ws; (void)ws_size;

  ushort* wh;  hipGetSymbolAddress((void**)&wh, HIP_SYMBOL(g_w_h));
  ushort* wl;  hipGetSymbolAddress((void**)&wl, HIP_SYMBOL(g_w_l));
  ushort* wl0h = wh, *wr0h = wh + DD * DD, *wl1h = wh + 2 * DD * DD, *wr1h = wh + 3 * DD * DD;
  ushort* wl0l = wl, *wr0l = wl + DD * DD, *wl1l = wl + 2 * DD * DD, *wr1l = wl + 3 * DD * DD;
  float* bf;   hipGetSymbolAddress((void**)&bf, HIP_SYMBOL(g_biasf));
  float* b0 = bf, *b1 = bf + DD;
  ushort* eh;  hipGetSymbolAddress((void**)&eh, HIP_SYMBOL(g_emb_h));
  ushort* el;  hipGetSymbolAddress((void**)&el, HIP_SYMBOL(g_emb_l));
  ushort* ah;  hipGetSymbolAddress((void**)&ah, HIP_SYMBOL(g_agg_h));
  ushort* al;  hipGetSymbolAddress((void**)&al, HIP_SYMBOL(g_agg_l));
  ushort* hh;  hipGetSymbolAddress((void**)&hh, HIP_SYMBOL(g_hh));
  ushort* hl;  hipGetSymbolAddress((void**)&hl, HIP_SYMBOL(g_hl));

  k_detect_ei<<<1, 256, 0, stream>>>(ei);
  k_detect_f<<<1, 256, 0, stream>>>((const ushort*)d_in[1]);

  // fused: emb split + 4 weight splits + bias cvt + bucket-count zero
  k_prep<<<PREP_GRID, 256, 0, stream>>>(d_in[1], d_in[2], d_in[4], d_in[5],
                                        d_in[7], d_in[3], d_in[6]);

  k_bucket<<<NBLK1, 256, 0, stream>>>(ei);
  k_bscan<<<1, 512, 0, stream>>>();
  k_place<<<NB, 256, 0, stream>>>();

  k_agg<<<NN / 4, 256, 0, stream>>>(eh);
  k_lin<0><<<LGRID, 256, 0, stream>>>(ah, al, eh, el, wl0h, wl0l, wr0h, wr0l, b0, hh, hl);
  k_agg<<<NN / 4, 256, 0, stream>>>(hh);
  k_lin<1><<<LGRID, 256, 0, stream>>>(ah, al, hh, hl, wl1h, wl1l, wr1h, wr1l, b1, d_out, nullptr);
}

// Round 6
// 507.643 us; speedup vs baseline: 1.3276x; 1.3276x over previous
//
#include <hip/hip_runtime.h>

typedef unsigned int uint;
typedef unsigned short ushort;
typedef __bf16 v8b __attribute__((ext_vector_type(8)));
typedef float v4f __attribute__((ext_vector_type(4)));

#define NN 100000
#define EE 3200000
#define DD 128

// counting-sort CSR build: 391 buckets x 256 nodes
#define BSH 8
#define BSZ 256                    // nodes per bucket (1<<BSH)
#define NB ((NN + BSZ - 1) / BSZ)  // 391
#define CAP 16384                  // per-bucket capacity (avg fill ~8184)
#define EPB 8192                   // edges per block in k_bucket
#define NBLK1 ((EE + EPB - 1) / EPB)  // 391

// k_lin: block = 4 waves x 32 rows = 128 rows
#define LGRID ((NN + 127) / 128)  // 782

// k_prep block ranges
#define PREP_EMB 12500            // NN*DD/4/256
#define PREP_WB 16                // blocks per weight matrix (DD*DD/4/256)
#define PREP_BIAS (PREP_EMB + 4 * PREP_WB)      // 12564
#define PREP_ZERO (PREP_BIAS + 1)               // 12565
#define PREP_GRID (PREP_ZERO + 2)               // 12567

// ---- all scratch static: zero dependence on ws_size ----
__device__ __attribute__((aligned(256))) int g_offs[NN + 1];
__device__ __attribute__((aligned(256))) int g_flag[2];    // [0]=edge is64, [1]=float is fp32
__device__ __attribute__((aligned(256))) int g_bcnt2[NB];  // bucket fill counts
__device__ __attribute__((aligned(256))) int g_bbase[NB];  // bucket base offsets (excl scan)
__device__ __attribute__((aligned(256))) int g_csr[EE];
// bucketed packed edges: (local_dst<<17)|src, bucket b at [b*CAP, b*CAP+cnt)
__device__ __attribute__((aligned(256))) uint g_pairs2[(size_t)NB * CAP];
// bf16 hi/lo split representations (hi also serves as the gather array)
__device__ __attribute__((aligned(256))) ushort g_emb_h[(size_t)NN * DD];
__device__ __attribute__((aligned(256))) ushort g_emb_l[(size_t)NN * DD];
__device__ __attribute__((aligned(256))) ushort g_agg_h[(size_t)NN * DD];
__device__ __attribute__((aligned(256))) ushort g_agg_l[(size_t)NN * DD];
__device__ __attribute__((aligned(256))) ushort g_hh[(size_t)NN * DD];
__device__ __attribute__((aligned(256))) ushort g_hl[(size_t)NN * DD];
__device__ __attribute__((aligned(256))) ushort g_w_h[4][DD * DD];  // Wl0,Wr0,Wl1,Wr1
__device__ __attribute__((aligned(256))) ushort g_w_l[4][DD * DD];
__device__ __attribute__((aligned(256))) float g_biasf[2][DD];  // b0,b1

__device__ __forceinline__ float blo(uint u) { return __uint_as_float(u << 16); }
__device__ __forceinline__ float bhi(uint u) { return __uint_as_float(u & 0xffff0000u); }
__device__ __forceinline__ ushort f2b(float f) {
  uint u = __float_as_uint(f);
  u += 0x7fffu + ((u >> 16) & 1u);  // RNE
  return (ushort)(u >> 16);
}
__device__ __forceinline__ float b2f(ushort s) { return __uint_as_float(((uint)s) << 16); }

// ---- dtype detection -----------------------------------------------------
__global__ void k_detect_ei(const int* __restrict__ ei) {
  __shared__ int any;
  if (threadIdx.x == 0) any = 0;
  __syncthreads();
  int v = 0;
  for (int i = threadIdx.x; i < 2048; i += 256) v |= ei[2 * i + 1];
  if (v) atomicOr(&any, 1);
  __syncthreads();
  if (threadIdx.x == 0) g_flag[0] = (any == 0) ? 1 : 0;  // 1 => int64
}

__global__ void k_detect_f(const ushort* __restrict__ u) {
  __shared__ int bad;
  if (threadIdx.x == 0) bad = 0;
  __syncthreads();
  int b = 0;
  for (int i = threadIdx.x; i < 2048; i += 256) {
    int e = (u[2 * i] >> 7) & 0xff;
    if (e < 0x40 || e > 0x7f) b = 1;
  }
  if (b) atomicOr(&bad, 1);
  __syncthreads();
  if (threadIdx.x == 0) g_flag[1] = bad;  // 1 => fp32
}

// ---- fused preprocessing: splits + bias cvt + bucket-count zero ---------
__device__ __forceinline__ void split4(const void* __restrict__ src,
                                       ushort* __restrict__ dh,
                                       ushort* __restrict__ dl, int i) {
  float f[4];
  if (g_flag[1]) {
    float4 v = *(const float4*)((const float*)src + i);
    f[0] = v.x; f[1] = v.y; f[2] = v.z; f[3] = v.w;
  } else {
    ushort4 s = *(const ushort4*)((const ushort*)src + i);
    f[0] = b2f(s.x); f[1] = b2f(s.y); f[2] = b2f(s.z); f[3] = b2f(s.w);
  }
  ushort4 h, l;
  ushort* hp = &h.x;
  ushort* lp = &l.x;
#pragma unroll
  for (int k = 0; k < 4; k++) {
    ushort hi = f2b(f[k]);
    hp[k] = hi;
    lp[k] = f2b(f[k] - b2f(hi));
  }
  *(ushort4*)(dh + i) = h;
  *(ushort4*)(dl + i) = l;
}

__global__ void k_prep(const void* __restrict__ emb, const void* __restrict__ s0,
                       const void* __restrict__ s1, const void* __restrict__ s2,
                       const void* __restrict__ s3, const void* __restrict__ bs0,
                       const void* __restrict__ bs1) {
  int bid = blockIdx.x;
  int tid = threadIdx.x;
  if (bid < PREP_EMB) {
    int i = (bid * 256 + tid) * 4;
    split4(emb, g_emb_h, g_emb_l, i);
  } else if (bid < PREP_BIAS) {
    int wb = bid - PREP_EMB;
    int w = wb >> 4;
    int i = ((wb & 15) * 256 + tid) * 4;
    const void* src = (w == 0) ? s0 : (w == 1) ? s1 : (w == 2) ? s2 : s3;
    split4(src, &g_w_h[0][0] + w * DD * DD, &g_w_l[0][0] + w * DD * DD, i);
  } else if (bid == PREP_BIAS) {
    int which = tid >> 7;        // 0 or 1
    int i = tid & 127;
    const void* src = which ? bs1 : bs0;
    float v = g_flag[1] ? ((const float*)src)[i] : b2f(((const ushort*)src)[i]);
    g_biasf[which][i] = v;
  } else {
    int i = (bid - PREP_ZERO) * 256 + tid;
    if (i < NB) g_bcnt2[i] = 0;
  }
}

__device__ __forceinline__ int ld_src(const int* __restrict__ ei, int is64, int e) {
  int v = is64 ? ei[2 * e] : ei[e];
  return ((uint)v < (uint)NN) ? v : 0;
}
__device__ __forceinline__ int ld_dst(const int* __restrict__ ei, int is64, int e) {
  int v = is64 ? ei[2 * (EE + e)] : ei[EE + e];
  return ((uint)v < (uint)NN) ? v : 0;
}

// ---------------- CSR build (counting sort, no per-edge global atomics) ----

// One pass over the edge stream. Per-block LDS staging of packed edges +
// 391-counter LDS histogram; ONE global atomicAdd per bucket per block
// (153K total); compact appends into fixed-capacity bucket regions.
// pack = (local_dst<<17)|src  (local<256 = 8b, src<131072 = 17b).
__global__ __launch_bounds__(256) void k_bucket(const int* __restrict__ ei) {
  int is64 = g_flag[0];
  __shared__ uint s_pk[EPB];    // 32 KB
  __shared__ ushort s_bk[EPB];  // 16 KB
  __shared__ int s_cnt[NB];
  __shared__ int s_base[NB];
  for (int i = threadIdx.x; i < NB; i += 256) s_cnt[i] = 0;
  __syncthreads();
  int base = blockIdx.x * EPB;
  // phase A: load, pack, count
#pragma unroll
  for (int i = 0; i < EPB / 256; i++) {
    int li = i * 256 + threadIdx.x;
    int e = base + li;
    uint pk = 0;
    int b = -1;
    if (e < EE) {
      int d = ld_dst(ei, is64, e);
      int s = ld_src(ei, is64, e);
      b = d >> BSH;
      pk = ((uint)(d & (BSZ - 1)) << 17) | (uint)s;
      atomicAdd(&s_cnt[b], 1);
    }
    s_pk[li] = pk;
    s_bk[li] = (ushort)b;  // 0xffff sentinel when invalid
  }
  __syncthreads();
  // reserve global bases: one atomic per non-empty bucket
  for (int i = threadIdx.x; i < NB; i += 256) {
    int c = s_cnt[i];
    s_base[i] = c ? atomicAdd(&g_bcnt2[i], c) : 0;
    s_cnt[i] = 0;  // reuse as cursor
  }
  __syncthreads();
  // phase B: append
#pragma unroll
  for (int i = 0; i < EPB / 256; i++) {
    int li = i * 256 + threadIdx.x;
    int b = s_bk[li];
    if (b != 0xffff) {
      int idx = s_base[b] + atomicAdd(&s_cnt[b], 1);
      if (idx < CAP) g_pairs2[(size_t)b * CAP + idx] = s_pk[li];
    }
  }
}

// exclusive scan of bucket counts -> bucket base offsets; total -> g_offs[NN]
__global__ void k_bscan() {
  __shared__ int sd[512];
  int t = threadIdx.x;
  int v = (t < NB) ? min(g_bcnt2[t], CAP) : 0;
  sd[t] = v;
  __syncthreads();
  for (int off = 1; off < 512; off <<= 1) {
    int x = (t >= off) ? sd[t - off] : 0;
    __syncthreads();
    sd[t] += x;
    __syncthreads();
  }
  if (t < NB) g_bbase[t] = sd[t] - v;
  if (t == 511) g_offs[NN] = sd[511];
}

// One block per bucket: LDS histogram of 256 local dsts, LDS scan, write
// g_offs for its 256 nodes (exclusive ownership - no atomics), then place
// srcs into g_csr via LDS cursors. Per-block working set ~64KB -> L2-local.
__global__ __launch_bounds__(256) void k_place() {
  int b = blockIdx.x;
  int n = min(g_bcnt2[b], CAP);
  int gbase = g_bbase[b];
  const uint* pr = g_pairs2 + (size_t)b * CAP;
  __shared__ int hist[BSZ];
  __shared__ int sd[BSZ];
  __shared__ int cur[BSZ];
  int t = threadIdx.x;
  hist[t] = 0;
  __syncthreads();
  for (int e = t; e < n; e += 256) atomicAdd(&hist[pr[e] >> 17], 1);
  __syncthreads();
  int v = hist[t];
  sd[t] = v;
  __syncthreads();
  for (int off = 1; off < BSZ; off <<= 1) {
    int x = (t >= off) ? sd[t - off] : 0;
    __syncthreads();
    sd[t] += x;
    __syncthreads();
  }
  int excl = sd[t] - v;
  int node = (b << BSH) + t;
  if (node < NN) g_offs[node] = gbase + excl;
  cur[t] = excl;
  __syncthreads();
  for (int e = t; e < n; e += 256) {
    uint pk = pr[e];
    int p = atomicAdd(&cur[pk >> 17], 1);
    g_csr[gbase + p] = (int)(pk & 0x1FFFFu);
  }
}

// ------- mean aggregation: bf16 gather, fp32 accum, hi/lo bf16 out -------
// One wave per node. uint4 gather: 16 lanes cover one 256B row, so each
// wave-instruction gathers FOUR edges. Measured (r4): bound by the L2-miss
// path at ~3.7 TB/s regardless of instruction mix; reuse math says tiling
// gains <=15% -> structurally near its limit. Left unchanged.
__global__ void k_agg(const ushort* __restrict__ x) {
  int lane = threadIdx.x & 63;
  int node = (blockIdx.x * blockDim.x + threadIdx.x) >> 6;
  int beg = g_offs[node], end = g_offs[node + 1];
  int eb = lane >> 4;          // quarter-wave id: which edge in group-of-4
  int col = (lane & 15) * 8;   // 8 bf16 cols per lane
  float a[8];
#pragma unroll
  for (int i = 0; i < 8; i++) a[i] = 0.f;
  for (int c = beg; c < end; c += 64) {
    int cnt = end - c;
    if (cnt > 64) cnt = 64;
    int my = g_csr[c + (lane < cnt ? lane : cnt - 1)];
    if ((uint)my >= (uint)NN) my = 0;
    int j = 0;
    for (; j + 8 <= cnt; j += 8) {
      int s0 = __shfl(my, j + eb);
      int s1 = __shfl(my, j + 4 + eb);
      uint4 r0 = *(const uint4*)(x + (size_t)s0 * DD + col);
      uint4 r1 = *(const uint4*)(x + (size_t)s1 * DD + col);
      a[0] += blo(r0.x); a[1] += bhi(r0.x);
      a[2] += blo(r0.y); a[3] += bhi(r0.y);
      a[4] += blo(r0.z); a[5] += bhi(r0.z);
      a[6] += blo(r0.w); a[7] += bhi(r0.w);
      a[0] += blo(r1.x); a[1] += bhi(r1.x);
      a[2] += blo(r1.y); a[3] += bhi(r1.y);
      a[4] += blo(r1.z); a[5] += bhi(r1.z);
      a[6] += blo(r1.w); a[7] += bhi(r1.w);
    }
    for (; j < cnt; j += 4) {
      int e = j + eb;
      int s = __shfl(my, e < cnt ? e : 0);
      float w = e < cnt ? 1.f : 0.f;
      uint4 r = *(const uint4*)(x + (size_t)s * DD + col);
      a[0] = fmaf(blo(r.x), w, a[0]); a[1] = fmaf(bhi(r.x), w, a[1]);
      a[2] = fmaf(blo(r.y), w, a[2]); a[3] = fmaf(bhi(r.y), w, a[3]);
      a[4] = fmaf(blo(r.z), w, a[4]); a[5] = fmaf(bhi(r.z), w, a[5]);
      a[6] = fmaf(blo(r.w), w, a[6]); a[7] = fmaf(bhi(r.w), w, a[7]);
    }
  }
#pragma unroll
  for (int i = 0; i < 8; i++) {
    a[i] += __shfl_xor(a[i], 16);
    a[i] += __shfl_xor(a[i], 32);
  }
  int deg = end - beg;
  float inv = deg > 0 ? 1.0f / (float)deg : 0.f;
  if (lane < 16) {
    uint4 h, l;
    uint* hp = &h.x;
    uint* lp = &l.x;
#pragma unroll
    for (int k = 0; k < 4; k++) {
      float f0 = a[2 * k] * inv, f1 = a[2 * k + 1] * inv;
      ushort h0 = f2b(f0), h1 = f2b(f1);
      ushort l0 = f2b(f0 - b2f(h0)), l1 = f2b(f1 - b2f(h1));
      hp[k] = (uint)h0 | ((uint)h1 << 16);
      lp[k] = (uint)l0 | ((uint)l1 << 16);
    }
    size_t o = (size_t)node * DD + col;
    *(uint4*)(g_agg_h + o) = h;
    *(uint4*)(g_agg_l + o) = l;
  }
}

// ------- MFMA linear, bf16x3: out = act(A1@Wl^T + b + A2@Wr^T) -----------
// (ah+al)(bh+bl) ~= ah*bh + ah*bl + al*bh  (error ~2^-16 rel, fp32 accum)
// Block = 4 waves x 32 rows = 128 rows.
// r5 lesson (FETCH 361MB, HBM-bound): A-loads inside the stage loop were
// re-fetched 4x with zero reuse. Fix: ALL A-fragments hoisted into regs
// ONCE (32 v8b = 128 VGPR, launch_bounds(256,2) -> <=256 VGPR cap), W
// staged per-32-rows in LDS (32 KB, XOR-swizzle cb16^=n&15; write & read
// use the same bijection; measured 0 bank conflicts, correctness passed).
// A frag: row=lane&15, k=(lane>>4)*8+j.  B frag: W row n=lane&15, same k.
// C/D: col=lane&15, row=(lane>>4)*4+reg.   (layouts verified: r4===r5 bitwise)
// MODE 0: bias+ReLU -> h hi/lo bf16.  MODE 1: bias+L2-normalize -> fp32 out.

#define MFMA16(a, b, c) __builtin_amdgcn_mfma_f32_16x16x32_bf16(a, b, c, 0, 0, 0)

template <int MODE>
__global__ __launch_bounds__(256, 2) void k_lin(
    const ushort* __restrict__ A1h, const ushort* __restrict__ A1l,
    const ushort* __restrict__ A2h, const ushort* __restrict__ A2l,
    const ushort* __restrict__ Wlh, const ushort* __restrict__ Wll,
    const ushort* __restrict__ Wrh, const ushort* __restrict__ Wrl,
    const float* __restrict__ bias, void* out0, ushort* __restrict__ outlo) {
  __shared__ ushort smem[16384];  // 4 arrays x 32 rows x 128 cols, 32 KB
  int tid = threadIdx.x;
  int lane = tid & 63;
  int wid = tid >> 6;
  int m = lane & 15, q = lane >> 4;
  int row0 = blockIdx.x * 128 + wid * 32;
  // clamp A-row addresses for the tail block (stores are guarded; no early
  // return because all waves must reach the staging __syncthreads)
  int arow0 = row0 + m;      if (arow0 > NN - 1) arow0 = NN - 1;
  int arow1 = row0 + 16 + m; if (arow1 > NN - 1) arow1 = NN - 1;
  size_t aoff0 = (size_t)arow0 * DD + q * 8;
  size_t aoff1 = (size_t)arow1 * DD + q * 8;
  // ---- load ALL A fragments once (32 v8b = 128 VGPR) ----
  v8b a1h[2][4], a1l[2][4], a2h[2][4], a2l[2][4];
#pragma unroll
  for (int ks = 0; ks < 4; ks++) {
    a1h[0][ks] = *(const v8b*)(A1h + aoff0 + ks * 32);
    a1l[0][ks] = *(const v8b*)(A1l + aoff0 + ks * 32);
    a2h[0][ks] = *(const v8b*)(A2h + aoff0 + ks * 32);
    a2l[0][ks] = *(const v8b*)(A2l + aoff0 + ks * 32);
    a1h[1][ks] = *(const v8b*)(A1h + aoff1 + ks * 32);
    a1l[1][ks] = *(const v8b*)(A1l + aoff1 + ks * 32);
    a2h[1][ks] = *(const v8b*)(A2h + aoff1 + ks * 32);
    a2l[1][ks] = *(const v8b*)(A2l + aoff1 + ks * 32);
  }
  v4f acc[2][8];
#pragma unroll
  for (int t = 0; t < 2; t++)
#pragma unroll
    for (int nt = 0; nt < 8; nt++) acc[t][nt] = (v4f){0.f, 0.f, 0.f, 0.f};
#pragma unroll
  for (int st = 0; st < 4; st++) {
    // ---- stage W rows [st*32, st*32+32) of all 4 arrays into LDS ----
#pragma unroll
    for (int k = 0; k < 8; k++) {
      int arr = k >> 1;  // compile-time after unroll
      int n = ((k & 1) << 4) + (tid >> 4);
      int cb16 = tid & 15;
      const ushort* srcp = (arr == 0) ? Wlh : (arr == 1) ? Wll : (arr == 2) ? Wrh : Wrl;
      uint4 v = *(const uint4*)(srcp + (size_t)(st * 32 + n) * DD + cb16 * 8);
      *(uint4*)(smem + arr * 4096 + n * 128 + ((cb16 ^ (n & 15)) << 3)) = v;
    }
    __syncthreads();
#pragma unroll
    for (int ks = 0; ks < 4; ks++) {
#pragma unroll
      for (int ntl = 0; ntl < 2; ntl++) {
        int nt = st * 2 + ntl;
        int nl = ntl * 16 + m;
        int u = nl * 128 + (((q + 4 * ks) ^ m) << 3);
        v8b blh = *(const v8b*)(smem + u);
        v8b bll = *(const v8b*)(smem + 4096 + u);
        v8b brh = *(const v8b*)(smem + 8192 + u);
        v8b brl = *(const v8b*)(smem + 12288 + u);
        acc[0][nt] = MFMA16(a1h[0][ks], blh, acc[0][nt]);
        acc[0][nt] = MFMA16(a1h[0][ks], bll, acc[0][nt]);
        acc[0][nt] = MFMA16(a1l[0][ks], blh, acc[0][nt]);
        acc[0][nt] = MFMA16(a2h[0][ks], brh, acc[0][nt]);
        acc[0][nt] = MFMA16(a2h[0][ks], brl, acc[0][nt]);
        acc[0][nt] = MFMA16(a2l[0][ks], brh, acc[0][nt]);
        acc[1][nt] = MFMA16(a1h[1][ks], blh, acc[1][nt]);
        acc[1][nt] = MFMA16(a1h[1][ks], bll, acc[1][nt]);
        acc[1][nt] = MFMA16(a1l[1][ks], blh, acc[1][nt]);
        acc[1][nt] = MFMA16(a2h[1][ks], brh, acc[1][nt]);
        acc[1][nt] = MFMA16(a2h[1][ks], brl, acc[1][nt]);
        acc[1][nt] = MFMA16(a2l[1][ks], brh, acc[1][nt]);
      }
    }
    __syncthreads();
  }
  if (MODE == 0) {
    ushort* oh = (ushort*)out0;
#pragma unroll
    for (int t = 0; t < 2; t++) {
#pragma unroll
      for (int nt = 0; nt < 8; nt++) {
        float bv = bias[nt * 16 + m];
#pragma unroll
        for (int r = 0; r < 4; r++) {
          int row = row0 + t * 16 + q * 4 + r;
          if (row < NN) {
            float v = acc[t][nt][r] + bv;
            v = v > 0.f ? v : 0.f;
            ushort hi = f2b(v);
            ushort lo = f2b(v - b2f(hi));
            size_t o = (size_t)row * DD + nt * 16 + m;
            oh[o] = hi;
            outlo[o] = lo;
          }
        }
      }
    }
  } else {
    float* of = (float*)out0;
#pragma unroll
    for (int t = 0; t < 2; t++) {
#pragma unroll
      for (int r = 0; r < 4; r++) {
        float p = 0.f;
#pragma unroll
        for (int nt = 0; nt < 8; nt++) {
          float v = acc[t][nt][r] + bias[nt * 16 + m];
          acc[t][nt][r] = v;
          p += v * v;
        }
        p += __shfl_xor(p, 1);
        p += __shfl_xor(p, 2);
        p += __shfl_xor(p, 4);
        p += __shfl_xor(p, 8);
        float inv = (p > 0.f) ? 1.0f / fmaxf(sqrtf(p), 1e-12f) : 0.f;
        int row = row0 + t * 16 + q * 4 + r;
        if (row < NN) {
#pragma unroll
          for (int nt = 0; nt < 8; nt++)
            of[(size_t)row * DD + nt * 16 + m] = acc[t][nt][r] * inv;
        }
      }
    }
  }
}

// ---------------- launch ----------------

extern "C" void kernel_launch(void* const* d_in, const int* in_sizes, int n_in,
                              void* d_out, int out_size, void* d_ws, size_t ws_size,
                              hipStream_t stream) {
  const int* ei = (const int*)d_in[0];
  (void)in_sizes; (void)n_in; (void)out_size; (void)d_ws; (void)ws_size;

  ushort* wh;  hipGetSymbolAddress((void**)&wh, HIP_SYMBOL(g_w_h));
  ushort* wl;  hipGetSymbolAddress((void**)&wl, HIP_SYMBOL(g_w_l));
  ushort* wl0h = wh, *wr0h = wh + DD * DD, *wl1h = wh + 2 * DD * DD, *wr1h = wh + 3 * DD * DD;
  ushort* wl0l = wl, *wr0l = wl + DD * DD, *wl1l = wl + 2 * DD * DD, *wr1l = wl + 3 * DD * DD;
  float* bf;   hipGetSymbolAddress((void**)&bf, HIP_SYMBOL(g_biasf));
  float* b0 = bf, *b1 = bf + DD;
  ushort* eh;  hipGetSymbolAddress((void**)&eh, HIP_SYMBOL(g_emb_h));
  ushort* el;  hipGetSymbolAddress((void**)&el, HIP_SYMBOL(g_emb_l));
  ushort* ah;  hipGetSymbolAddress((void**)&ah, HIP_SYMBOL(g_agg_h));
  ushort* al;  hipGetSymbolAddress((void**)&al, HIP_SYMBOL(g_agg_l));
  ushort* hh;  hipGetSymbolAddress((void**)&hh, HIP_SYMBOL(g_hh));
  ushort* hl;  hipGetSymbolAddress((void**)&hl, HIP_SYMBOL(g_hl));

  k_detect_ei<<<1, 256, 0, stream>>>(ei);
  k_detect_f<<<1, 256, 0, stream>>>((const ushort*)d_in[1]);

  // fused: emb split + 4 weight splits + bias cvt + bucket-count zero
  k_prep<<<PREP_GRID, 256, 0, stream>>>(d_in[1], d_in[2], d_in[4], d_in[5],
                                        d_in[7], d_in[3], d_in[6]);

  k_bucket<<<NBLK1, 256, 0, stream>>>(ei);
  k_bscan<<<1, 512, 0, stream>>>();
  k_place<<<NB, 256, 0, stream>>>();

  k_agg<<<NN / 4, 256, 0, stream>>>(eh);
  k_lin<0><<<LGRID, 256, 0, stream>>>(ah, al, eh, el, wl0h, wl0l, wr0h, wr0l, b0, hh, hl);
  k_agg<<<NN / 4, 256, 0, stream>>>(hh);
  k_lin<1><<<LGRID, 256, 0, stream>>>(ah, al, hh, hl, wl1h, wl1l, wr1h, wr1l, b1, d_out, nullptr);
}

// Round 7
// 495.083 us; speedup vs baseline: 1.3612x; 1.0254x over previous
//
#include <hip/hip_runtime.h>

typedef unsigned int uint;
typedef unsigned short ushort;
typedef __bf16 v8b __attribute__((ext_vector_type(8)));
typedef float v4f __attribute__((ext_vector_type(4)));

#define NN 100000
#define EE 3200000
#define DD 128

// counting-sort CSR build: 391 buckets x 256 nodes
#define BSH 8
#define BSZ 256                    // nodes per bucket (1<<BSH)
#define NB ((NN + BSZ - 1) / BSZ)  // 391
#define CAP 16384                  // per-bucket capacity (avg fill ~8184)
#define EPB 8192                   // edges per block in bucket role
#define NBLK1 ((EE + EPB - 1) / EPB)  // 391

// k_lin: block = 4 waves x 32 rows = 128 rows
#define LGRID ((NN + 127) / 128)  // 782

// fused prep+bucket block ranges
#define PB_B0 NBLK1               // 391: end of bucket role
#define PB_EMBB 12500             // NN*DD/4/256
#define PB_B1 (PB_B0 + PB_EMBB)   // start of weight blocks
#define PB_WB 64                  // 4 matrices x 16 blocks
#define PB_B2 (PB_B1 + PB_WB)     // bias block
#define PB_GRID (PB_B2 + 1)

// ---- all scratch static: zero dependence on ws_size ----
__device__ __attribute__((aligned(256))) int g_offs[NN + 1];
__device__ __attribute__((aligned(256))) int g_bcnt2[NB];  // bucket fill counts (zeroed by k_place tail)
__device__ __attribute__((aligned(256))) int g_bbase[NB];  // bucket base offsets (excl scan)
__device__ __attribute__((aligned(256))) int g_csr[EE];
// bucketed packed edges: (local_dst<<17)|src, bucket b at [b*CAP, b*CAP+cnt)
__device__ __attribute__((aligned(256))) uint g_pairs2[(size_t)NB * CAP];
// bf16 hi/lo split representations (hi also serves as the gather array)
__device__ __attribute__((aligned(256))) ushort g_emb_h[(size_t)NN * DD];
__device__ __attribute__((aligned(256))) ushort g_emb_l[(size_t)NN * DD];
__device__ __attribute__((aligned(256))) ushort g_agg_h[(size_t)NN * DD];
__device__ __attribute__((aligned(256))) ushort g_agg_l[(size_t)NN * DD];
__device__ __attribute__((aligned(256))) ushort g_hh[(size_t)NN * DD];
__device__ __attribute__((aligned(256))) ushort g_hl[(size_t)NN * DD];
__device__ __attribute__((aligned(256))) ushort g_w_h[4][DD * DD];  // Wl0,Wr0,Wl1,Wr1
__device__ __attribute__((aligned(256))) ushort g_w_l[4][DD * DD];
__device__ __attribute__((aligned(256))) float g_biasf[2][DD];  // b0,b1

__device__ __forceinline__ float blo(uint u) { return __uint_as_float(u << 16); }
__device__ __forceinline__ float bhi(uint u) { return __uint_as_float(u & 0xffff0000u); }
__device__ __forceinline__ ushort f2b(float f) {
  uint u = __float_as_uint(f);
  u += 0x7fffu + ((u >> 16) & 1u);  // RNE
  return (ushort)(u >> 16);
}
__device__ __forceinline__ float b2f(ushort s) { return __uint_as_float(((uint)s) << 16); }

__device__ __forceinline__ int ld_src(const int* __restrict__ ei, int is64, int e) {
  int v = is64 ? ei[2 * e] : ei[e];
  return ((uint)v < (uint)NN) ? v : 0;
}
__device__ __forceinline__ int ld_dst(const int* __restrict__ ei, int is64, int e) {
  int v = is64 ? ei[2 * (EE + e)] : ei[EE + e];
  return ((uint)v < (uint)NN) ? v : 0;
}

// ---- bf16 hi/lo split of 4 consecutive elements (explicit dtype flag) ----
__device__ __forceinline__ void split4f(const void* __restrict__ src,
                                        ushort* __restrict__ dh,
                                        ushort* __restrict__ dl, int i, int isf32) {
  float f[4];
  if (isf32) {
    float4 v = *(const float4*)((const float*)src + i);
    f[0] = v.x; f[1] = v.y; f[2] = v.z; f[3] = v.w;
  } else {
    ushort4 s = *(const ushort4*)((const ushort*)src + i);
    f[0] = b2f(s.x); f[1] = b2f(s.y); f[2] = b2f(s.z); f[3] = b2f(s.w);
  }
  ushort4 h, l;
  ushort* hp = &h.x;
  ushort* lp = &l.x;
#pragma unroll
  for (int k = 0; k < 4; k++) {
    ushort hi = f2b(f[k]);
    hp[k] = hi;
    lp[k] = f2b(f[k] - b2f(hi));
  }
  *(ushort4*)(dh + i) = h;
  *(ushort4*)(dl + i) = l;
}

// ---- fused prep + bucket (independent work overlapped in one launch) ----
// Roles by blockIdx: [0,391) bucket; [391,12891) emb split; [12891,12955)
// weight split; 12955 bias. Each block self-detects its source dtype
// (bucket: OR of 2048 odd ints of its OWN edge range -> is64; prep: bf16
// exponent test on the emb/weight header, L2-hot). No g_flag kernel, no
// separate zero pass (g_bcnt2 zeroed by k_place tail / static init).
// Bucket staging in REGISTERS (pk[32] + packed bucket ids) -> LDS 3 KB,
// so prep's streaming occupancy is not harmed by the fusion.
__global__ __launch_bounds__(256) void k_pb(
    const int* __restrict__ ei, const void* __restrict__ emb,
    const void* __restrict__ s0, const void* __restrict__ s1,
    const void* __restrict__ s2, const void* __restrict__ s3,
    const void* __restrict__ bs0, const void* __restrict__ bs1) {
  __shared__ int s_cnt[NB];
  __shared__ int s_base[NB];
  __shared__ int s_flag;
  int bid = blockIdx.x;
  int tid = threadIdx.x;
  if (bid < PB_B0) {
    // ---------------- bucket role ----------------
    if (tid == 0) s_flag = 0;
    for (int i = tid; i < NB; i += 256) s_cnt[i] = 0;
    __syncthreads();
    int base = bid * EPB;
    // per-block is64 detection: sample 2048 odd ints of own range
    // (indices 2e+1 < 2*EE are in-bounds for both int32 and int64 layouts)
    int v = 0;
#pragma unroll
    for (int k = 0; k < 8; k++) {
      int e = base + k * 256 + tid;
      if (e < EE) v |= ei[2 * e + 1];
    }
    if (v) atomicOr(&s_flag, 1);
    __syncthreads();
    int is64 = (s_flag == 0) ? 1 : 0;
    uint pk[32];
    uint bb[16];
    // phase A: load into regs, LDS histogram
#pragma unroll
    for (int k = 0; k < 32; k++) {
      int e = base + k * 256 + tid;
      uint b = 0xffffu;
      uint p = 0;
      if (e < EE) {
        int d = ld_dst(ei, is64, e);
        int s = ld_src(ei, is64, e);
        b = (uint)(d >> BSH);
        p = ((uint)(d & (BSZ - 1)) << 17) | (uint)s;
        atomicAdd(&s_cnt[(int)b], 1);
      }
      pk[k] = p;
      if ((k & 1) == 0) bb[k >> 1] = b;
      else bb[k >> 1] |= b << 16;
    }
    __syncthreads();
    // reserve global bases: one atomic per non-empty bucket
    for (int i = tid; i < NB; i += 256) {
      int c = s_cnt[i];
      s_base[i] = c ? atomicAdd(&g_bcnt2[i], c) : 0;
      s_cnt[i] = 0;  // reuse as cursor
    }
    __syncthreads();
    // phase B: append from regs
#pragma unroll
    for (int k = 0; k < 32; k++) {
      uint b = (bb[k >> 1] >> ((k & 1) * 16)) & 0xffffu;
      if (b != 0xffffu) {
        int idx = s_base[b] + atomicAdd(&s_cnt[b], 1);
        if (idx < CAP) g_pairs2[(size_t)b * CAP + idx] = pk[k];
      }
    }
  } else {
    // ---------------- prep roles ----------------
    if (tid == 0) s_flag = 0;
    __syncthreads();
    const ushort* u = (const ushort*)emb;  // all prep roles key dtype off emb
    int bad = 0;
    for (int i = tid; i < 2048; i += 256) {
      int e = (u[2 * i] >> 7) & 0xff;
      if (e < 0x40 || e > 0x7f) bad = 1;
    }
    if (bad) atomicOr(&s_flag, 1);
    __syncthreads();
    int isf32 = s_flag;
    if (bid < PB_B1) {
      int i = ((bid - PB_B0) * 256 + tid) * 4;
      split4f(emb, g_emb_h, g_emb_l, i, isf32);
    } else if (bid < PB_B2) {
      int wb = bid - PB_B1;
      int w = wb >> 4;
      int i = ((wb & 15) * 256 + tid) * 4;
      const void* src = (w == 0) ? s0 : (w == 1) ? s1 : (w == 2) ? s2 : s3;
      split4f(src, &g_w_h[0][0] + w * DD * DD, &g_w_l[0][0] + w * DD * DD, i, isf32);
    } else {
      int which = tid >> 7;  // 0 or 1
      int i = tid & 127;
      const void* src = which ? bs1 : bs0;
      float vv = isf32 ? ((const float*)src)[i] : b2f(((const ushort*)src)[i]);
      g_biasf[which][i] = vv;
    }
  }
}

// exclusive scan of bucket counts -> bucket base offsets; total -> g_offs[NN]
__global__ void k_bscan() {
  __shared__ int sd[512];
  int t = threadIdx.x;
  int v = (t < NB) ? min(g_bcnt2[t], CAP) : 0;
  sd[t] = v;
  __syncthreads();
  for (int off = 1; off < 512; off <<= 1) {
    int x = (t >= off) ? sd[t - off] : 0;
    __syncthreads();
    sd[t] += x;
    __syncthreads();
  }
  if (t < NB) g_bbase[t] = sd[t] - v;
  if (t == 511) g_offs[NN] = sd[511];
}

// One block per bucket: LDS histogram of 256 local dsts, LDS scan, write
// g_offs for its 256 nodes (exclusive ownership - no atomics), then place
// srcs into g_csr via LDS cursors. Tail: zero own g_bcnt2[b] for the next
// launch (k_pb's atomics must never race a zeroing pass).
__global__ __launch_bounds__(256) void k_place() {
  int b = blockIdx.x;
  int n = min(g_bcnt2[b], CAP);
  int gbase = g_bbase[b];
  const uint* pr = g_pairs2 + (size_t)b * CAP;
  __shared__ int hist[BSZ];
  __shared__ int sd[BSZ];
  __shared__ int cur[BSZ];
  int t = threadIdx.x;
  hist[t] = 0;
  __syncthreads();
  for (int e = t; e < n; e += 256) atomicAdd(&hist[pr[e] >> 17], 1);
  __syncthreads();
  int v = hist[t];
  sd[t] = v;
  __syncthreads();
  for (int off = 1; off < BSZ; off <<= 1) {
    int x = (t >= off) ? sd[t - off] : 0;
    __syncthreads();
    sd[t] += x;
    __syncthreads();
  }
  int excl = sd[t] - v;
  int node = (b << BSH) + t;
  if (node < NN) g_offs[node] = gbase + excl;
  cur[t] = excl;
  __syncthreads();
  for (int e = t; e < n; e += 256) {
    uint pk = pr[e];
    int p = atomicAdd(&cur[pk >> 17], 1);
    g_csr[gbase + p] = (int)(pk & 0x1FFFFu);
  }
  __syncthreads();
  if (t == 0) g_bcnt2[b] = 0;
}

// ------- mean aggregation: bf16 gather, fp32 accum, hi/lo bf16 out -------
// One wave per node. uint4 gather: 16 lanes cover one 256B row, so each
// wave-instruction gathers FOUR edges. Bound by the L2-miss path (~3.7
// TB/s effective, FETCH 354MB) - r4/r6 measured. 16-edge inner step keeps
// 4 loads in flight and quarters the shuffle count.
__global__ void k_agg(const ushort* __restrict__ x) {
  int lane = threadIdx.x & 63;
  int node = (blockIdx.x * blockDim.x + threadIdx.x) >> 6;
  int beg = g_offs[node], end = g_offs[node + 1];
  int eb = lane >> 4;          // quarter-wave id: which edge in group-of-4
  int col = (lane & 15) * 8;   // 8 bf16 cols per lane
  float a[8];
#pragma unroll
  for (int i = 0; i < 8; i++) a[i] = 0.f;
  for (int c = beg; c < end; c += 64) {
    int cnt = end - c;
    if (cnt > 64) cnt = 64;
    int my = g_csr[c + (lane < cnt ? lane : cnt - 1)];
    if ((uint)my >= (uint)NN) my = 0;
    int j = 0;
    for (; j + 16 <= cnt; j += 16) {
      int s0 = __shfl(my, j + eb);
      int s1 = __shfl(my, j + 4 + eb);
      int s2 = __shfl(my, j + 8 + eb);
      int s3 = __shfl(my, j + 12 + eb);
      uint4 r0 = *(const uint4*)(x + (size_t)s0 * DD + col);
      uint4 r1 = *(const uint4*)(x + (size_t)s1 * DD + col);
      uint4 r2 = *(const uint4*)(x + (size_t)s2 * DD + col);
      uint4 r3 = *(const uint4*)(x + (size_t)s3 * DD + col);
      a[0] += blo(r0.x); a[1] += bhi(r0.x); a[2] += blo(r0.y); a[3] += bhi(r0.y);
      a[4] += blo(r0.z); a[5] += bhi(r0.z); a[6] += blo(r0.w); a[7] += bhi(r0.w);
      a[0] += blo(r1.x); a[1] += bhi(r1.x); a[2] += blo(r1.y); a[3] += bhi(r1.y);
      a[4] += blo(r1.z); a[5] += bhi(r1.z); a[6] += blo(r1.w); a[7] += bhi(r1.w);
      a[0] += blo(r2.x); a[1] += bhi(r2.x); a[2] += blo(r2.y); a[3] += bhi(r2.y);
      a[4] += blo(r2.z); a[5] += bhi(r2.z); a[6] += blo(r2.w); a[7] += bhi(r2.w);
      a[0] += blo(r3.x); a[1] += bhi(r3.x); a[2] += blo(r3.y); a[3] += bhi(r3.y);
      a[4] += blo(r3.z); a[5] += bhi(r3.z); a[6] += blo(r3.w); a[7] += bhi(r3.w);
    }
    for (; j + 8 <= cnt; j += 8) {
      int s0 = __shfl(my, j + eb);
      int s1 = __shfl(my, j + 4 + eb);
      uint4 r0 = *(const uint4*)(x + (size_t)s0 * DD + col);
      uint4 r1 = *(const uint4*)(x + (size_t)s1 * DD + col);
      a[0] += blo(r0.x); a[1] += bhi(r0.x); a[2] += blo(r0.y); a[3] += bhi(r0.y);
      a[4] += blo(r0.z); a[5] += bhi(r0.z); a[6] += blo(r0.w); a[7] += bhi(r0.w);
      a[0] += blo(r1.x); a[1] += bhi(r1.x); a[2] += blo(r1.y); a[3] += bhi(r1.y);
      a[4] += blo(r1.z); a[5] += bhi(r1.z); a[6] += blo(r1.w); a[7] += bhi(r1.w);
    }
    for (; j < cnt; j += 4) {
      int e = j + eb;
      int s = __shfl(my, e < cnt ? e : 0);
      float w = e < cnt ? 1.f : 0.f;
      uint4 r = *(const uint4*)(x + (size_t)s * DD + col);
      a[0] = fmaf(blo(r.x), w, a[0]); a[1] = fmaf(bhi(r.x), w, a[1]);
      a[2] = fmaf(blo(r.y), w, a[2]); a[3] = fmaf(bhi(r.y), w, a[3]);
      a[4] = fmaf(blo(r.z), w, a[4]); a[5] = fmaf(bhi(r.z), w, a[5]);
      a[6] = fmaf(blo(r.w), w, a[6]); a[7] = fmaf(bhi(r.w), w, a[7]);
    }
  }
#pragma unroll
  for (int i = 0; i < 8; i++) {
    a[i] += __shfl_xor(a[i], 16);
    a[i] += __shfl_xor(a[i], 32);
  }
  int deg = end - beg;
  float inv = deg > 0 ? 1.0f / (float)deg : 0.f;
  if (lane < 16) {
    uint4 h, l;
    uint* hp = &h.x;
    uint* lp = &l.x;
#pragma unroll
    for (int k = 0; k < 4; k++) {
      float f0 = a[2 * k] * inv, f1 = a[2 * k + 1] * inv;
      ushort h0 = f2b(f0), h1 = f2b(f1);
      ushort l0 = f2b(f0 - b2f(h0)), l1 = f2b(f1 - b2f(h1));
      hp[k] = (uint)h0 | ((uint)h1 << 16);
      lp[k] = (uint)l0 | ((uint)l1 << 16);
    }
    size_t o = (size_t)node * DD + col;
    *(uint4*)(g_agg_h + o) = h;
    *(uint4*)(g_agg_l + o) = l;
  }
}

// ------- MFMA linear, bf16x3: out = act(A1@Wl^T + b + A2@Wr^T) -----------
// (ah+al)(bh+bl) ~= ah*bh + ah*bl + al*bh  (error ~2^-16 rel, fp32 accum)
// Block = 4 waves x 32 rows. A-fragments hoisted into regs ONCE (128
// VGPR); W staged per-32-rows in LDS (32 KB, XOR-swizzle cb16^=n&15;
// write & read use the same bijection; measured 0 bank conflicts).
// A frag: row=lane&15, k=(lane>>4)*8+j.  B frag: W row n=lane&15, same k.
// C/D: col=lane&15, row=(lane>>4)*4+reg.   (layouts verified bitwise)
// MODE 0: bias+ReLU -> h hi/lo bf16.  MODE 1: bias+L2-normalize -> fp32 out.

#define MFMA16(a, b, c) __builtin_amdgcn_mfma_f32_16x16x32_bf16(a, b, c, 0, 0, 0)

template <int MODE>
__global__ __launch_bounds__(256, 2) void k_lin(
    const ushort* __restrict__ A1h, const ushort* __restrict__ A1l,
    const ushort* __restrict__ A2h, const ushort* __restrict__ A2l,
    const ushort* __restrict__ Wlh, const ushort* __restrict__ Wll,
    const ushort* __restrict__ Wrh, const ushort* __restrict__ Wrl,
    const float* __restrict__ bias, void* out0, ushort* __restrict__ outlo) {
  __shared__ ushort smem[16384];  // 4 arrays x 32 rows x 128 cols, 32 KB
  int tid = threadIdx.x;
  int lane = tid & 63;
  int wid = tid >> 6;
  int m = lane & 15, q = lane >> 4;
  int row0 = blockIdx.x * 128 + wid * 32;
  // clamp A-row addresses for the tail block (stores are guarded; no early
  // return because all waves must reach the staging __syncthreads)
  int arow0 = row0 + m;      if (arow0 > NN - 1) arow0 = NN - 1;
  int arow1 = row0 + 16 + m; if (arow1 > NN - 1) arow1 = NN - 1;
  size_t aoff0 = (size_t)arow0 * DD + q * 8;
  size_t aoff1 = (size_t)arow1 * DD + q * 8;
  // ---- load ALL A fragments once (32 v8b = 128 VGPR) ----
  v8b a1h[2][4], a1l[2][4], a2h[2][4], a2l[2][4];
#pragma unroll
  for (int ks = 0; ks < 4; ks++) {
    a1h[0][ks] = *(const v8b*)(A1h + aoff0 + ks * 32);
    a1l[0][ks] = *(const v8b*)(A1l + aoff0 + ks * 32);
    a2h[0][ks] = *(const v8b*)(A2h + aoff0 + ks * 32);
    a2l[0][ks] = *(const v8b*)(A2l + aoff0 + ks * 32);
    a1h[1][ks] = *(const v8b*)(A1h + aoff1 + ks * 32);
    a1l[1][ks] = *(const v8b*)(A1l + aoff1 + ks * 32);
    a2h[1][ks] = *(const v8b*)(A2h + aoff1 + ks * 32);
    a2l[1][ks] = *(const v8b*)(A2l + aoff1 + ks * 32);
  }
  v4f acc[2][8];
#pragma unroll
  for (int t = 0; t < 2; t++)
#pragma unroll
    for (int nt = 0; nt < 8; nt++) acc[t][nt] = (v4f){0.f, 0.f, 0.f, 0.f};
#pragma unroll
  for (int st = 0; st < 4; st++) {
    // ---- stage W rows [st*32, st*32+32) of all 4 arrays into LDS ----
#pragma unroll
    for (int k = 0; k < 8; k++) {
      int arr = k >> 1;  // compile-time after unroll
      int n = ((k & 1) << 4) + (tid >> 4);
      int cb16 = tid & 15;
      const ushort* srcp = (arr == 0) ? Wlh : (arr == 1) ? Wll : (arr == 2) ? Wrh : Wrl;
      uint4 v = *(const uint4*)(srcp + (size_t)(st * 32 + n) * DD + cb16 * 8);
      *(uint4*)(smem + arr * 4096 + n * 128 + ((cb16 ^ (n & 15)) << 3)) = v;
    }
    __syncthreads();
#pragma unroll
    for (int ks = 0; ks < 4; ks++) {
#pragma unroll
      for (int ntl = 0; ntl < 2; ntl++) {
        int nt = st * 2 + ntl;
        int nl = ntl * 16 + m;
        int u = nl * 128 + (((q + 4 * ks) ^ m) << 3);
        v8b blh = *(const v8b*)(smem + u);
        v8b bll = *(const v8b*)(smem + 4096 + u);
        v8b brh = *(const v8b*)(smem + 8192 + u);
        v8b brl = *(const v8b*)(smem + 12288 + u);
        acc[0][nt] = MFMA16(a1h[0][ks], blh, acc[0][nt]);
        acc[0][nt] = MFMA16(a1h[0][ks], bll, acc[0][nt]);
        acc[0][nt] = MFMA16(a1l[0][ks], blh, acc[0][nt]);
        acc[0][nt] = MFMA16(a2h[0][ks], brh, acc[0][nt]);
        acc[0][nt] = MFMA16(a2h[0][ks], brl, acc[0][nt]);
        acc[0][nt] = MFMA16(a2l[0][ks], brh, acc[0][nt]);
        acc[1][nt] = MFMA16(a1h[1][ks], blh, acc[1][nt]);
        acc[1][nt] = MFMA16(a1h[1][ks], bll, acc[1][nt]);
        acc[1][nt] = MFMA16(a1l[1][ks], blh, acc[1][nt]);
        acc[1][nt] = MFMA16(a2h[1][ks], brh, acc[1][nt]);
        acc[1][nt] = MFMA16(a2h[1][ks], brl, acc[1][nt]);
        acc[1][nt] = MFMA16(a2l[1][ks], brh, acc[1][nt]);
      }
    }
    __syncthreads();
  }
  if (MODE == 0) {
    ushort* oh = (ushort*)out0;
#pragma unroll
    for (int t = 0; t < 2; t++) {
#pragma unroll
      for (int nt = 0; nt < 8; nt++) {
        float bv = bias[nt * 16 + m];
#pragma unroll
        for (int r = 0; r < 4; r++) {
          int row = row0 + t * 16 + q * 4 + r;
          if (row < NN) {
            float v = acc[t][nt][r] + bv;
            v = v > 0.f ? v : 0.f;
            ushort hi = f2b(v);
            ushort lo = f2b(v - b2f(hi));
            size_t o = (size_t)row * DD + nt * 16 + m;
            oh[o] = hi;
            outlo[o] = lo;
          }
        }
      }
    }
  } else {
    float* of = (float*)out0;
#pragma unroll
    for (int t = 0; t < 2; t++) {
#pragma unroll
      for (int r = 0; r < 4; r++) {
        float p = 0.f;
#pragma unroll
        for (int nt = 0; nt < 8; nt++) {
          float v = acc[t][nt][r] + bias[nt * 16 + m];
          acc[t][nt][r] = v;
          p += v * v;
        }
        p += __shfl_xor(p, 1);
        p += __shfl_xor(p, 2);
        p += __shfl_xor(p, 4);
        p += __shfl_xor(p, 8);
        float inv = (p > 0.f) ? 1.0f / fmaxf(sqrtf(p), 1e-12f) : 0.f;
        int row = row0 + t * 16 + q * 4 + r;
        if (row < NN) {
#pragma unroll
          for (int nt = 0; nt < 8; nt++)
            of[(size_t)row * DD + nt * 16 + m] = acc[t][nt][r] * inv;
        }
      }
    }
  }
}

// ---------------- launch ----------------

extern "C" void kernel_launch(void* const* d_in, const int* in_sizes, int n_in,
                              void* d_out, int out_size, void* d_ws, size_t ws_size,
                              hipStream_t stream) {
  const int* ei = (const int*)d_in[0];
  (void)in_sizes; (void)n_in; (void)out_size; (void)d_ws; (void)ws_size;

  ushort* wh;  hipGetSymbolAddress((void**)&wh, HIP_SYMBOL(g_w_h));
  ushort* wl;  hipGetSymbolAddress((void**)&wl, HIP_SYMBOL(g_w_l));
  ushort* wl0h = wh, *wr0h = wh + DD * DD, *wl1h = wh + 2 * DD * DD, *wr1h = wh + 3 * DD * DD;
  ushort* wl0l = wl, *wr0l = wl + DD * DD, *wl1l = wl + 2 * DD * DD, *wr1l = wl + 3 * DD * DD;
  float* bf;   hipGetSymbolAddress((void**)&bf, HIP_SYMBOL(g_biasf));
  float* b0 = bf, *b1 = bf + DD;
  ushort* eh;  hipGetSymbolAddress((void**)&eh, HIP_SYMBOL(g_emb_h));
  ushort* el;  hipGetSymbolAddress((void**)&el, HIP_SYMBOL(g_emb_l));
  ushort* ah;  hipGetSymbolAddress((void**)&ah, HIP_SYMBOL(g_agg_h));
  ushort* al;  hipGetSymbolAddress((void**)&al, HIP_SYMBOL(g_agg_l));
  ushort* hh;  hipGetSymbolAddress((void**)&hh, HIP_SYMBOL(g_hh));
  ushort* hl;  hipGetSymbolAddress((void**)&hl, HIP_SYMBOL(g_hl));

  // fused prep + bucket (self-detecting dtypes, no zero pass)
  k_pb<<<PB_GRID, 256, 0, stream>>>(ei, d_in[1], d_in[2], d_in[4], d_in[5],
                                    d_in[7], d_in[3], d_in[6]);
  k_bscan<<<1, 512, 0, stream>>>();
  k_place<<<NB, 256, 0, stream>>>();

  k_agg<<<NN / 4, 256, 0, stream>>>(eh);
  k_lin<0><<<LGRID, 256, 0, stream>>>(ah, al, eh, el, wl0h, wl0l, wr0h, wr0l, b0, hh, hl);
  k_agg<<<NN / 4, 256, 0, stream>>>(hh);
  k_lin<1><<<LGRID, 256, 0, stream>>>(ah, al, hh, hl, wl1h, wl1l, wr1h, wr1l, b1, d_out, nullptr);
}